// Round 12
// baseline (201.441 us; speedup 1.0000x reference)
//
#include <hip/hip_runtime.h>
#include <hip/hip_bf16.h>
#include <hip/hip_cooperative_groups.h>
#include <math.h>

namespace cg = cooperative_groups;

#define HMAP 800
#define WMAP 800
#define OHW  120
#define NCELL (OHW * OHW)
#define NCH  8
#define NPTS 100000
#define SDIM 32
#define CAP  32
#define NBIN1 121
#define NBINS (NBIN1 * NBIN1)     // 14641

#define NBLK 1024                 // cooperative grid: 4 blocks/CU x 256 CUs

__device__ __forceinline__ float rscale() { return 800.0f / 120.0f; }

__device__ __forceinline__ float clipval(float v) {
    if (isnan(v)) v = 0.f;
    else if (isinf(v)) v = (v > 0.f) ? 0.f : -3.4028234663852886e38f;
    if (v > 255.f) v = 255.f;
    return v;
}

__device__ __forceinline__ float norm_sum(int i) {
    const float r = rscale();
    float c = ((float)i + 0.5f) * r - 0.5f;
    int j0 = (int)ceilf(c - r);
    float s = 0.f;
#pragma unroll
    for (int k = 0; k < 14; ++k) {
        int j = j0 + k;
        if (j < 0 || j >= HMAP) continue;
        s += fmaxf(0.f, 1.f - fabsf(c - (float)j) / r);
    }
    return s;
}

// ---------------- workspace layout (int units) ----------------
#define WS_COUNTS   0
#define WS_SPILLCUR 14641
#define WS_INVS     14656
#define WS_ENTRIES  14784
#define WS_SPILL    (WS_ENTRIES + NBINS * CAP * 2)
#define WS_T        (WS_SPILL + NPTS * 2)
#define WS_END      (WS_T + NCH * WMAP * OHW)
#define WS_REQ_BYTES ((size_t)WS_END * 4)

#define FILLT       ((NPTS + 1023) / 1024)            // 98 fill tasks (1024 pts each)
#define RYT         (NCH * WMAP / 2)                  // 3200 RY tasks (2 rows each)
#define GA_BLOCKS   (NCELL / 4)                       // 3600 = 8 * 450
#define RX_BLOCKS   (NCH * OHW / 2)                   // 480

// ================= task bodies (shared by mono + split paths) =================

__device__ __forceinline__ void task_fill(int t, const int* __restrict__ loc,
                                          int* __restrict__ counts,
                                          int2* __restrict__ entries,
                                          int2* __restrict__ spill,
                                          int* __restrict__ spill_cur) {
    int base = t * 1024 + threadIdx.x;
    const float r = rscale();
#pragma unroll
    for (int k = 0; k < 4; ++k) {            // 4 independent atomic chains
        int n = base + k * 256;
        if (n >= NPTS) break;
        int2 xy = ((const int2*)loc)[n];
        int x = min(max(xy.x, 0), WMAP - 1);
        int y = min(max(xy.y, 0), HMAP - 1);
        int iy0 = (int)floorf(((float)y + 0.5f) / r - 0.5f);
        int ix0 = (int)floorf(((float)x + 0.5f) / r - 0.5f);
        int bin = (iy0 + 1) * NBIN1 + (ix0 + 1);
        int pos = (y << 10) | x;
        int slot = atomicAdd(&counts[bin], 1);
        if (slot < CAP) {
            entries[(size_t)bin * CAP + slot] = make_int2(n, pos);
        } else {
            int s = atomicAdd(spill_cur, 1);
            if (s < NPTS) spill[s] = make_int2((bin << 17) | n, pos);
        }
    }
}

__device__ __forceinline__ void task_ry(int t, const float* __restrict__ spatial,
                                        float* __restrict__ T, float* __restrict__ row) {
    int rsel = threadIdx.x >> 7;
    int hw = threadIdx.x & 127;
    int bx = t * 2 + rsel;
    int c = bx / WMAP, xx = bx % WMAP;
    const float* rp = spatial + (size_t)c * (HMAP * WMAP) + (size_t)xx * WMAP;
    for (int j = hw; j < HMAP; j += 128) row[rsel * HMAP + j] = clipval(rp[j]);
    __syncthreads();
    int oy = hw;
    if (oy < OHW) {
        const float r = rscale();
        const float invR = 1.0f / r;
        float cy = ((float)oy + 0.5f) * r - 0.5f;
        int y0 = (int)ceilf(cy - r);
        float acc = 0.f, ws = 0.f;
#pragma unroll
        for (int k = 0; k < 14; ++k) {
            int j = y0 + k;
            float w = fmaxf(0.f, fmaf(-fabsf(cy - (float)j), invR, 1.f));
            w = (j >= 0 && j < HMAP) ? w : 0.f;
            int jc = min(max(j, 0), HMAP - 1);
            ws += w;
            acc = fmaf(w, row[rsel * HMAP + HMAP - 1 - jc], acc);
        }
        T[((size_t)c * WMAP + xx) * OHW + oy] = acc / (255.f * ws);
    }
}

__device__ __forceinline__ void task_gather(int t, const float* __restrict__ emb,
                                            const int* __restrict__ counts,
                                            const int2* __restrict__ entries,
                                            const int2* __restrict__ spill,
                                            const int* __restrict__ spill_cur,
                                            const float* __restrict__ invS,
                                            float* __restrict__ out,
                                            int2* __restrict__ stf) {
    // XCD-aware band swizzle (bijective, 3600 = 8*450)
    int sbid = (t & 7) * (GA_BLOCKS / 8) + (t >> 3);
    int tid = threadIdx.x;
    int wv = tid >> 6;
    int cell = sbid * 4 + wv;
    int lane = tid & 63;
    int g = lane >> 4;
    int c2 = lane & 15;
    int iy = cell / OHW, ix = cell % OHW;
    const float r = rscale();
    const float invR = 1.0f / r;
    float cy = ((float)iy + 0.5f) * r - 0.5f;
    float cx = ((float)ix + 0.5f) * r - 0.5f;
    float invS2 = invS[iy] * invS[ix];
    int b00 = iy * NBIN1 + ix;

    int mybin = b00 + (g >> 1) * NBIN1 + (g & 1);
    int craw = counts[mybin];
    bool ovfany = __any(craw > CAP);
    int cnt = min(craw, CAP);
    int cmax = cnt;
    cmax = max(cmax, __shfl_xor(cmax, 16));
    cmax = max(cmax, __shfl_xor(cmax, 32));

    int2* st = stf + wv * 4 * CAP;     // [4][CAP] per wave
#pragma unroll
    for (int ch = 0; ch < 2; ++ch) {
        int binrow = b00 + ch * NBIN1;
        const int2* base = entries + (size_t)binrow * CAP;
        int2 e = base[lane];
        int gs = ch * 2 + (lane >> 5);
        int slot = lane & 31;
        int scnt = min(counts[binrow + (lane >> 5)], CAP);
        int idx = 0;
        float w = 0.f;
        if (slot < scnt) {
            float py = (float)((e.y >> 10) & 1023);
            float px = (float)(e.y & 1023);
            float wy = fmaxf(0.f, fmaf(-fabsf(cy - py), invR, 1.f));
            float wx = fmaxf(0.f, fmaf(-fabsf(cx - px), invR, 1.f));
            w = wy * wx * invS2;
            idx = e.x;
        }
        st[gs * CAP + slot] = make_int2(idx, __float_as_int(w));
    }
    // wave-local LDS write->read; compiler inserts lgkmcnt waits

    const float2* embp = (const float2*)emb;
    float ax = 0.f, ay = 0.f;
    for (int i = 0; i < cmax; i += 4) {
        int2 s0 = st[g * CAP + i + 0];
        int2 s1 = st[g * CAP + i + 1];
        int2 s2 = st[g * CAP + i + 2];
        int2 s3 = st[g * CAP + i + 3];
        float2 v0 = embp[(size_t)s0.x * (SDIM / 2) + c2];
        float2 v1 = embp[(size_t)s1.x * (SDIM / 2) + c2];
        float2 v2 = embp[(size_t)s2.x * (SDIM / 2) + c2];
        float2 v3 = embp[(size_t)s3.x * (SDIM / 2) + c2];
        float w0 = __int_as_float(s0.y), w1_ = __int_as_float(s1.y);
        float w2_ = __int_as_float(s2.y), w3 = __int_as_float(s3.y);
        ax = fmaf(w0, v0.x, ax); ay = fmaf(w0, v0.y, ay);
        ax = fmaf(w1_, v1.x, ax); ay = fmaf(w1_, v1.y, ay);
        ax = fmaf(w2_, v2.x, ax); ay = fmaf(w2_, v2.y, ay);
        ax = fmaf(w3, v3.x, ax); ay = fmaf(w3, v3.y, ay);
    }

    if (ovfany) {
        int sn = min(spill_cur[0], NPTS);
        for (int s = 0; s < sn; ++s) {
            int2 e = spill[s];
            if ((e.x >> 17) == mybin) {
                int n = e.x & 0x1FFFF;
                float py = (float)((e.y >> 10) & 1023);
                float px = (float)(e.y & 1023);
                float wy = fmaxf(0.f, fmaf(-fabsf(cy - py), invR, 1.f));
                float wx = fmaxf(0.f, fmaf(-fabsf(cx - px), invR, 1.f));
                float w = wy * wx * invS2;
                float2 v = embp[(size_t)n * (SDIM / 2) + c2];
                ax = fmaf(w, v.x, ax); ay = fmaf(w, v.y, ay);
            }
        }
    }

    ax += __shfl_xor(ax, 16); ay += __shfl_xor(ay, 16);
    ax += __shfl_xor(ax, 32); ay += __shfl_xor(ay, 32);
    if (lane < 16) {
        out[(size_t)(NCH + 2 * c2) * NCELL + cell] = ax;
        out[(size_t)(NCH + 2 * c2 + 1) * NCELL + cell] = ay;
    }
}

__device__ __forceinline__ void task_rx(int t, const float* __restrict__ T,
                                        const float* __restrict__ invS,
                                        float* __restrict__ out) {
    int col = t * 2 + (threadIdx.x >> 7);
    int oy = threadIdx.x & 127;
    if (oy >= OHW) return;   // safe: no syncs inside
    int c = col / OHW, ox = col % OHW;
    const float r = rscale();
    const float invR = 1.0f / r;
    float cx = ((float)ox + 0.5f) * r - 0.5f;
    int x0 = (int)ceilf(cx - r);
    float acc = 0.f;
#pragma unroll
    for (int k = 0; k < 14; ++k) {
        int j = x0 + k;
        float w = fmaxf(0.f, fmaf(-fabsf(cx - (float)j), invR, 1.f));
        w = (j >= 0 && j < WMAP) ? w : 0.f;
        int jc = min(max(j, 0), WMAP - 1);
        acc = fmaf(w, T[((size_t)c * WMAP + jc) * OHW + oy], acc);
    }
    out[((size_t)c * OHW + oy) * OHW + ox] = acc * invS[ox];
}

__device__ __forceinline__ void task_mlp(const float* __restrict__ scalar,
                                         const float* __restrict__ w1,
                                         const float* __restrict__ b1,
                                         const float* __restrict__ w2,
                                         const float* __restrict__ b2,
                                         float* __restrict__ out,
                                         float* __restrict__ sh) {
    int j = threadIdx.x;
    if (j < 32) {
        float a = b1[j];
        for (int i = 0; i < 8; ++i) a = fmaf(scalar[i], w1[i * 32 + j], a);
        sh[j] = fmaxf(a, 0.f);
    }
    __syncthreads();
    if (j < 4) {
        float a = b2[j];
        for (int i = 0; i < 32; ++i) a = fmaf(sh[i], w2[i * 4 + j], a);
        out[(size_t)(NCH + SDIM) * NCELL + j] = fmaxf(a, 0.f);
    }
}

// ================= monolithic cooperative kernel =================
__global__ __launch_bounds__(256, 4)
void k_mono(const float* __restrict__ spatial, const int* __restrict__ loc,
            const float* __restrict__ emb, const float* __restrict__ scalar,
            const float* __restrict__ w1, const float* __restrict__ b1,
            const float* __restrict__ w2, const float* __restrict__ b2,
            int* __restrict__ counts, float* __restrict__ invS,
            int2* __restrict__ entries, int2* __restrict__ spill,
            int* __restrict__ spill_cur, float* __restrict__ T,
            float* __restrict__ out) {
    cg::grid_group grid = cg::this_grid();
    __shared__ __align__(16) char smem[2 * HMAP * 4];   // 6400 B (>= gather's 4224)
    int bid = blockIdx.x;

    // ---- phase A: zero counts+cursor, build invS ----
    {
        int gid = bid * 256 + threadIdx.x;
        if (gid < 14656) counts[gid] = 0;
        if (gid < OHW) invS[gid] = 1.0f / norm_sum(gid);
    }
    grid.sync();

    // ---- phase B: fill (latency) overlapped with resizeY (bandwidth) ----
    for (int t = bid; t < FILLT + RYT; t += NBLK) {
        if (t < FILLT) task_fill(t, loc, counts, entries, spill, spill_cur);
        else           task_ry(t - FILLT, spatial, T, (float*)smem);
        __syncthreads();     // LDS reuse across iterations
    }
    grid.sync();

    // ---- phase C: gather + resizeX + MLP ----
    for (int t = bid; t < GA_BLOCKS + RX_BLOCKS + 1; t += NBLK) {
        if (t < GA_BLOCKS)
            task_gather(t, emb, counts, entries, spill, spill_cur, invS, out,
                        (int2*)smem);
        else if (t < GA_BLOCKS + RX_BLOCKS)
            task_rx(t - GA_BLOCKS, T, invS, out);
        else
            task_mlp(scalar, w1, b1, w2, b2, out, (float*)smem);
        __syncthreads();     // LDS reuse across iterations
    }
}

// ================= split-path kernels (fallback if coop launch fails) ========
__global__ void k_zero(int* __restrict__ counts, float* __restrict__ invS) {
    int gid = blockIdx.x * 256 + threadIdx.x;
    if (gid < 14656) counts[gid] = 0;
    if (gid < OHW) invS[gid] = 1.0f / norm_sum(gid);
}

__global__ void k_phase1(const float* __restrict__ spatial, const int* __restrict__ loc,
                         float* __restrict__ T, int* __restrict__ counts,
                         int2* __restrict__ entries, int2* __restrict__ spill,
                         int* __restrict__ spill_cur) {
    __shared__ float row[2][HMAP];
    if (blockIdx.x < FILLT) {
        task_fill(blockIdx.x, loc, counts, entries, spill, spill_cur);
        return;
    }
    task_ry(blockIdx.x - FILLT, spatial, T, &row[0][0]);
}

__global__ void k_phase2(const float* __restrict__ T, const float* __restrict__ emb,
                         const int* __restrict__ counts, const int2* __restrict__ entries,
                         const int2* __restrict__ spill, const int* __restrict__ spill_cur,
                         const float* __restrict__ invS, float* __restrict__ out,
                         const float* __restrict__ scalar, const float* __restrict__ w1,
                         const float* __restrict__ b1, const float* __restrict__ w2,
                         const float* __restrict__ b2) {
    __shared__ __align__(16) char smem[4224];
    int bid = blockIdx.x;
    if (bid < GA_BLOCKS) {
        task_gather(bid, emb, counts, entries, spill, spill_cur, invS, out,
                    (int2*)smem);
        return;
    }
    if (bid < GA_BLOCKS + RX_BLOCKS) {
        task_rx(bid - GA_BLOCKS, T, invS, out);
        return;
    }
    task_mlp(scalar, w1, b1, w2, b2, out, (float*)smem);
}

// ================= minimal fallback (ws too small) ==============
__global__ void k_norm_fb(float* __restrict__ S) {
    int i = blockIdx.x * blockDim.x + threadIdx.x;
    if (i < OHW) S[i] = norm_sum(i);
}

__global__ void k_spatial_fb(const float* __restrict__ spatial, const float* __restrict__ S,
                             float* __restrict__ out) {
    int t = blockIdx.x * blockDim.x + threadIdx.x;
    if (t >= NCH * NCELL) return;
    int c = t / NCELL, rem = t % NCELL;
    int oy = rem / OHW, ox = rem % OHW;
    const float r = rscale();
    float cy = ((float)oy + 0.5f) * r - 0.5f;
    float cx = ((float)ox + 0.5f) * r - 0.5f;
    int y0 = (int)ceilf(cy - r);
    int x0 = (int)ceilf(cx - r);
    const float* sp = spatial + (size_t)c * (HMAP * WMAP);
    float acc = 0.f;
    for (int kx = 0; kx < 14; ++kx) {
        int col = x0 + kx;
        if (col < 0 || col >= WMAP) continue;
        float wxx = fmaxf(0.f, 1.f - fabsf(cx - (float)col) / r);
        if (wxx == 0.f) continue;
        const float* colp = sp + (size_t)col * WMAP;
        float accy = 0.f;
        for (int ky = 0; ky < 14; ++ky) {
            int j = y0 + ky;
            if (j < 0 || j >= HMAP) continue;
            float wyy = fmaxf(0.f, 1.f - fabsf(cy - (float)j) / r);
            accy = fmaf(wyy, clipval(colp[HMAP - 1 - j]), accy);
        }
        acc = fmaf(wxx, accy, acc);
    }
    out[t] = acc * (1.0f / 255.0f) / (S[oy] * S[ox]);
}

__global__ void k_scatter_fb(const float* __restrict__ emb, const int* __restrict__ loc,
                             const float* __restrict__ S, float* __restrict__ out) {
    int t = blockIdx.x * blockDim.x + threadIdx.x;
    if (t >= NPTS * SDIM) return;
    int n = t >> 5, c = t & 31;
    int x = min(max(loc[2 * n + 0], 0), WMAP - 1);
    int y = min(max(loc[2 * n + 1], 0), HMAP - 1);
    float e = emb[t];
    const float r = rscale();
    int iy0 = (int)floorf(((float)y + 0.5f) / r - 0.5f);
    int ix0 = (int)floorf(((float)x + 0.5f) / r - 0.5f);
    float* base = out + (size_t)(NCH + c) * NCELL;
#pragma unroll
    for (int a = 0; a < 2; ++a) {
        int iy = iy0 + a;
        if (iy < 0 || iy >= OHW) continue;
        float cyv = ((float)iy + 0.5f) * r - 0.5f;
        float wy = fmaxf(0.f, 1.f - fabsf(cyv - (float)y) / r) / S[iy];
#pragma unroll
        for (int b = 0; b < 2; ++b) {
            int ix = ix0 + b;
            if (ix < 0 || ix >= OHW) continue;
            float cxv = ((float)ix + 0.5f) * r - 0.5f;
            float wx = fmaxf(0.f, 1.f - fabsf(cxv - (float)x) / r) / S[ix];
            atomicAdd(base + iy * OHW + ix, e * wy * wx);
        }
    }
}

__global__ void k_mlp_fb(const float* __restrict__ scalar, const float* __restrict__ w1,
                         const float* __restrict__ b1, const float* __restrict__ w2,
                         const float* __restrict__ b2, float* __restrict__ out) {
    __shared__ float h[32];
    task_mlp(scalar, w1, b1, w2, b2, out, h);
}

extern "C" void kernel_launch(void* const* d_in, const int* in_sizes, int n_in,
                              void* d_out, int out_size, void* d_ws, size_t ws_size,
                              hipStream_t stream) {
    const float* spatial = (const float*)d_in[0];
    const float* emb     = (const float*)d_in[1];
    const int*   loc     = (const int*)d_in[2];
    const float* scalar  = (const float*)d_in[3];
    const float* w1      = (const float*)d_in[4];
    const float* b1      = (const float*)d_in[5];
    const float* w2      = (const float*)d_in[6];
    const float* b2      = (const float*)d_in[7];
    float* out = (float*)d_out;

    int*   wsi = (int*)d_ws;
    float* wsf = (float*)d_ws;

    if (ws_size >= WS_REQ_BYTES) {
        int*   counts    = wsi + WS_COUNTS;
        int*   spill_cur = wsi + WS_SPILLCUR;
        float* invS      = wsf + WS_INVS;
        int2*  entries   = (int2*)(wsi + WS_ENTRIES);
        int2*  spill     = (int2*)(wsi + WS_SPILL);
        float* T         = wsf + WS_T;

        void* args[] = {(void*)&spatial, (void*)&loc, (void*)&emb, (void*)&scalar,
                        (void*)&w1, (void*)&b1, (void*)&w2, (void*)&b2,
                        (void*)&counts, (void*)&invS, (void*)&entries, (void*)&spill,
                        (void*)&spill_cur, (void*)&T, (void*)&out};
        hipError_t e = hipLaunchCooperativeKernel((void*)k_mono, dim3(NBLK), dim3(256),
                                                  args, 0, stream);
        if (e != hipSuccess) {   // fallback: proven 3-kernel split path
            k_zero<<<58, 256, 0, stream>>>(counts, invS);
            k_phase1<<<FILLT + RYT, 256, 0, stream>>>(spatial, loc, T, counts,
                                                      entries, spill, spill_cur);
            k_phase2<<<GA_BLOCKS + RX_BLOCKS + 1, 256, 0, stream>>>(
                T, emb, counts, entries, spill, spill_cur, invS, out,
                scalar, w1, b1, w2, b2);
        }
    } else {
        float* S = wsf;
        hipMemsetAsync(d_out, 0, (size_t)out_size * sizeof(float), stream);
        k_norm_fb<<<1, 128, 0, stream>>>(S);
        k_spatial_fb<<<(NCH * NCELL + 255) / 256, 256, 0, stream>>>(spatial, S, out);
        k_scatter_fb<<<(NPTS * SDIM + 255) / 256, 256, 0, stream>>>(emb, loc, S, out);
        k_mlp_fb<<<1, 64, 0, stream>>>(scalar, w1, b1, w2, b2, out);
    }
}

// Round 13
// 33.840 us; speedup vs baseline: 5.9527x; 5.9527x over previous
//
#include <hip/hip_runtime.h>
#include <hip/hip_bf16.h>
#include <math.h>

#define HMAP 800
#define WMAP 800
#define OHW  120
#define NCELL (OHW * OHW)
#define NCH  8
#define NPTS 100000
#define SDIM 32
#define CAP  16
#define NBIN1 121                 // bins per dim: iy0 in [-1,119] -> +1
#define NBINS (NBIN1 * NBIN1)     // 14641

__device__ __forceinline__ float rscale() { return 800.0f / 120.0f; }

__device__ __forceinline__ float clipval(float v) {
    if (isnan(v)) v = 0.f;
    else if (isinf(v)) v = (v > 0.f) ? 0.f : -3.4028234663852886e38f;
    if (v > 255.f) v = 255.f;
    return v;
}

// normalization sum for output index i (same for both dims, both 800->120)
__device__ __forceinline__ float norm_sum(int i) {
    const float r = rscale();
    float c = ((float)i + 0.5f) * r - 0.5f;
    int j0 = (int)ceilf(c - r);
    float s = 0.f;
#pragma unroll
    for (int k = 0; k < 14; ++k) {
        int j = j0 + k;
        if (j < 0 || j >= HMAP) continue;
        s += fmaxf(0.f, 1.f - fabsf(c - (float)j) / r);
    }
    return s;
}

// ---------------- workspace layout (int units) ----------------
#define WS_COUNTS   0
#define WS_SPILLCUR 14641
#define WS_INVS     14656
#define WS_ENTRIES  14784
#define WS_SPILL    (WS_ENTRIES + NBINS * CAP * 2)
#define WS_T        (WS_SPILL + NPTS * 2)
#define WS_END      (WS_T + NCH * WMAP * OHW)
#define WS_REQ_BYTES ((size_t)WS_END * 4)

#define Z_BLOCKS    58                                // 58*256 >= 14656
#define FILLB       ((NPTS + 1023) / 1024)            // 98 blocks, 4 pts/thread
#define RY_BLOCKS   (NCH * WMAP / 2)                  // 3200 (2 rows per block)
#define GA_BLOCKS   (NCELL / 4)                       // 3600 = 8 * 450
#define RX_BLOCKS   (NCH * OHW / 2)                   // 480

// ===== K0: zero counts+cursor, compute invS table =====
__global__ void k_zero(int* __restrict__ counts, float* __restrict__ invS) {
    int gid = blockIdx.x * 256 + threadIdx.x;
    if (gid < 14656) counts[gid] = 0;
    if (gid < OHW) invS[gid] = 1.0f / norm_sum(gid);
}

// ===== K1: point binning w/ 4-deep ILP (blocks [0,98)) + LDS resize Y =====
__global__ void k_phase1(const float* __restrict__ spatial, const int* __restrict__ loc,
                         float* __restrict__ T, int* __restrict__ counts,
                         int2* __restrict__ entries, int2* __restrict__ spill,
                         int* __restrict__ spill_cur) {
    __shared__ float row[2][HMAP];
    if (blockIdx.x < FILLB) {
        int base = blockIdx.x * 1024 + threadIdx.x;
        const float r = rscale();
#pragma unroll
        for (int k = 0; k < 4; ++k) {            // 4 independent atomic chains
            int n = base + k * 256;              // coalesced int2 loads per round
            if (n >= NPTS) break;
            int2 xy = ((const int2*)loc)[n];
            int x = min(max(xy.x, 0), WMAP - 1);
            int y = min(max(xy.y, 0), HMAP - 1);
            int iy0 = (int)floorf(((float)y + 0.5f) / r - 0.5f);
            int ix0 = (int)floorf(((float)x + 0.5f) / r - 0.5f);
            int bin = (iy0 + 1) * NBIN1 + (ix0 + 1);
            int pos = (y << 10) | x;
            int slot = atomicAdd(&counts[bin], 1);
            if (slot < CAP) {
                entries[(size_t)bin * CAP + slot] = make_int2(n, pos);
            } else {  // rare overflow: append to spill list (scanned by gather)
                int s = atomicAdd(spill_cur, 1);
                if (s < NPTS) spill[s] = make_int2((bin << 17) | n, pos);
            }
        }
        return;
    }
    // ---- resize Y: 2 rows (c,xx) per 256-thread block; T[c][xx][oy] ----
    int bx = (blockIdx.x - FILLB) * 2 + (threadIdx.x >> 7);
    int hw = threadIdx.x & 127;
    int rsel = threadIdx.x >> 7;
    int c = bx / WMAP, xx = bx % WMAP;
    const float* rp = spatial + (size_t)c * (HMAP * WMAP) + (size_t)xx * WMAP;
    for (int j = hw; j < HMAP; j += 128) row[rsel][j] = clipval(rp[j]);
    __syncthreads();
    int oy = hw;
    if (oy >= OHW) return;
    const float r = rscale();
    const float invR = 1.0f / r;
    float cy = ((float)oy + 0.5f) * r - 0.5f;
    int y0 = (int)ceilf(cy - r);
    float acc = 0.f, ws = 0.f;
#pragma unroll
    for (int k = 0; k < 14; ++k) {
        int j = y0 + k;
        float w = fmaxf(0.f, fmaf(-fabsf(cy - (float)j), invR, 1.f));
        w = (j >= 0 && j < HMAP) ? w : 0.f;           // branchless OOB zero
        int jc = min(max(j, 0), HMAP - 1);
        ws += w;
        acc = fmaf(w, row[rsel][HMAP - 1 - jc], acc);
    }
    T[((size_t)c * WMAP + xx) * OHW + oy] = acc / (255.f * ws);
}

// ===== K2: gather (blocks [0,3600)) + resizeX ([3600,4080)) + MLP (4080) =====
__global__ void k_phase2(const float* __restrict__ T, const float* __restrict__ emb,
                         const int* __restrict__ counts, const int2* __restrict__ entries,
                         const int2* __restrict__ spill, const int* __restrict__ spill_cur,
                         const float* __restrict__ invS, float* __restrict__ out,
                         const float* __restrict__ scalar, const float* __restrict__ w1,
                         const float* __restrict__ b1, const float* __restrict__ w2,
                         const float* __restrict__ b2) {
    __shared__ int2 st[4][4][CAP];    // [wave][group/bin][slot] = (emb idx, weight bits)
    __shared__ float sh[32];
    int bid = blockIdx.x;
    if (bid < GA_BLOCKS) {
        // XCD-aware band swizzle: keep vertical-neighbor bin reuse in one XCD's L2.
        int sbid = (bid & 7) * (GA_BLOCKS / 8) + (bid >> 3);   // bijective, 3600=8*450
        int t = threadIdx.x;
        int wv = t >> 6;
        int cell = sbid * 4 + wv;
        int lane = t & 63;
        int g = lane >> 4;            // bin group 0..3 (dy=g>>1, dx=g&1)
        int c2 = lane & 15;           // channel pair
        int iy = cell / OHW, ix = cell % OHW;
        const float r = rscale();
        const float invR = 1.0f / r;
        float cy = ((float)iy + 0.5f) * r - 0.5f;
        float cx = ((float)ix + 0.5f) * r - 0.5f;
        float invS2 = invS[iy] * invS[ix];
        int b00 = iy * NBIN1 + ix;

        // my main-loop bin
        int mybin = b00 + (g >> 1) * NBIN1 + (g & 1);
        int craw = counts[mybin];
        bool ovfany = __any(craw > CAP);
        int cnt = min(craw, CAP);
        int cmax = cnt;
        cmax = max(cmax, __shfl_xor(cmax, 16));
        cmax = max(cmax, __shfl_xor(cmax, 32));

        // stage: one coalesced 512B chunk covers 4 bins x 16 slots (1 entry/lane);
        // weight precomputed (0 for empty slots). gs = lane>>4 matches group g order.
        {
            int gs = lane >> 4;
            int slot = lane & 15;
            int binst = b00 + (gs >> 1) * NBIN1 + (gs & 1);
            // bins (b00,b00+1) and (b00+NBIN1,b00+NBIN1+1) are memory-adjacent:
            int2 e = entries[(size_t)(b00 + (lane >> 5) * NBIN1) * CAP + (lane & 31)];
            int scnt = min(counts[binst], CAP);
            int idx = 0;
            float w = 0.f;
            if (slot < scnt) {
                float py = (float)((e.y >> 10) & 1023);
                float px = (float)(e.y & 1023);
                float wy = fmaxf(0.f, fmaf(-fabsf(cy - py), invR, 1.f));
                float wx = fmaxf(0.f, fmaf(-fabsf(cx - px), invR, 1.f));
                w = wy * wx * invS2;
                idx = e.x;
            }
            st[wv][gs][slot] = make_int2(idx, __float_as_int(w));
        }
        // wave-local LDS write->read; compiler inserts lgkmcnt waits

        const float2* embp = (const float2*)emb;
        float ax = 0.f, ay = 0.f;
        for (int i = 0; i < cmax; i += 4) {           // i+3 <= 15 always
            int2 s0 = st[wv][g][i + 0];
            int2 s1 = st[wv][g][i + 1];
            int2 s2 = st[wv][g][i + 2];
            int2 s3 = st[wv][g][i + 3];
            float2 v0 = embp[(size_t)s0.x * (SDIM / 2) + c2];
            float2 v1 = embp[(size_t)s1.x * (SDIM / 2) + c2];
            float2 v2 = embp[(size_t)s2.x * (SDIM / 2) + c2];
            float2 v3 = embp[(size_t)s3.x * (SDIM / 2) + c2];
            float w0 = __int_as_float(s0.y), w1_ = __int_as_float(s1.y);
            float w2_ = __int_as_float(s2.y), w3 = __int_as_float(s3.y);
            ax = fmaf(w0, v0.x, ax); ay = fmaf(w0, v0.y, ay);
            ax = fmaf(w1_, v1.x, ax); ay = fmaf(w1_, v1.y, ay);
            ax = fmaf(w2_, v2.x, ax); ay = fmaf(w2_, v2.y, ay);
            ax = fmaf(w3, v3.x, ax); ay = fmaf(w3, v3.y, ay);
        }

        if (ovfany) {                                  // rare: scan spill list
            int sn = min(spill_cur[0], NPTS);
            for (int s = 0; s < sn; ++s) {
                int2 e = spill[s];
                if ((e.x >> 17) == mybin) {
                    int n = e.x & 0x1FFFF;
                    float py = (float)((e.y >> 10) & 1023);
                    float px = (float)(e.y & 1023);
                    float wy = fmaxf(0.f, fmaf(-fabsf(cy - py), invR, 1.f));
                    float wx = fmaxf(0.f, fmaf(-fabsf(cx - px), invR, 1.f));
                    float w = wy * wx * invS2;
                    float2 v = embp[(size_t)n * (SDIM / 2) + c2];
                    ax = fmaf(w, v.x, ax); ay = fmaf(w, v.y, ay);
                }
            }
        }

        ax += __shfl_xor(ax, 16); ay += __shfl_xor(ay, 16);
        ax += __shfl_xor(ax, 32); ay += __shfl_xor(ay, 32);
        if (lane < 16) {
            out[(size_t)(NCH + 2 * c2) * NCELL + cell] = ax;
            out[(size_t)(NCH + 2 * c2 + 1) * NCELL + cell] = ay;
        }
        return;
    }
    if (bid < GA_BLOCKS + RX_BLOCKS) {   // resize X: 2 (c,ox) columns per block
        int col = (bid - GA_BLOCKS) * 2 + (threadIdx.x >> 7);
        int oy = threadIdx.x & 127;
        if (oy >= OHW) return;
        int c = col / OHW, ox = col % OHW;
        const float r = rscale();
        const float invR = 1.0f / r;
        float cx = ((float)ox + 0.5f) * r - 0.5f;
        int x0 = (int)ceilf(cx - r);
        float acc = 0.f;
#pragma unroll
        for (int k = 0; k < 14; ++k) {
            int j = x0 + k;
            float w = fmaxf(0.f, fmaf(-fabsf(cx - (float)j), invR, 1.f));
            w = (j >= 0 && j < WMAP) ? w : 0.f;
            int jc = min(max(j, 0), WMAP - 1);
            acc = fmaf(w, T[((size_t)c * WMAP + jc) * OHW + oy], acc);
        }
        out[((size_t)c * OHW + oy) * OHW + ox] = acc * invS[ox];
        return;
    }
    // ---- fused scalar MLP ----
    int j = threadIdx.x;
    if (j < 32) {
        float a = b1[j];
        for (int i = 0; i < 8; ++i) a = fmaf(scalar[i], w1[i * 32 + j], a);
        sh[j] = fmaxf(a, 0.f);
    }
    __syncthreads();
    if (j < 4) {
        float a = b2[j];
        for (int i = 0; i < 32; ++i) a = fmaf(sh[i], w2[i * 4 + j], a);
        out[(size_t)(NCH + SDIM) * NCELL + j] = fmaxf(a, 0.f);
    }
}

// ================= fallback path (ws too small): round-1 style ==============
__global__ void k_norm_fb(float* __restrict__ S) {
    int i = blockIdx.x * blockDim.x + threadIdx.x;
    if (i < OHW) S[i] = norm_sum(i);
}

__global__ void k_spatial_fb(const float* __restrict__ spatial, const float* __restrict__ S,
                             float* __restrict__ out) {
    int t = blockIdx.x * blockDim.x + threadIdx.x;
    if (t >= NCH * NCELL) return;
    int c = t / NCELL, rem = t % NCELL;
    int oy = rem / OHW, ox = rem % OHW;
    const float r = rscale();
    float cy = ((float)oy + 0.5f) * r - 0.5f;
    float cx = ((float)ox + 0.5f) * r - 0.5f;
    int y0 = (int)ceilf(cy - r);
    int x0 = (int)ceilf(cx - r);
    const float* sp = spatial + (size_t)c * (HMAP * WMAP);
    float acc = 0.f;
    for (int kx = 0; kx < 14; ++kx) {
        int col = x0 + kx;
        if (col < 0 || col >= WMAP) continue;
        float wxx = fmaxf(0.f, 1.f - fabsf(cx - (float)col) / r);
        if (wxx == 0.f) continue;
        const float* colp = sp + (size_t)col * WMAP;
        float accy = 0.f;
        for (int ky = 0; ky < 14; ++ky) {
            int j = y0 + ky;
            if (j < 0 || j >= HMAP) continue;
            float wyy = fmaxf(0.f, 1.f - fabsf(cy - (float)j) / r);
            accy = fmaf(wyy, clipval(colp[HMAP - 1 - j]), accy);
        }
        acc = fmaf(wxx, accy, acc);
    }
    out[t] = acc * (1.0f / 255.0f) / (S[oy] * S[ox]);
}

__global__ void k_scatter_fb(const float* __restrict__ emb, const int* __restrict__ loc,
                             const float* __restrict__ S, float* __restrict__ out) {
    int t = blockIdx.x * blockDim.x + threadIdx.x;
    if (t >= NPTS * SDIM) return;
    int n = t >> 5, c = t & 31;
    int x = min(max(loc[2 * n + 0], 0), WMAP - 1);
    int y = min(max(loc[2 * n + 1], 0), HMAP - 1);
    float e = emb[t];
    const float r = rscale();
    int iy0 = (int)floorf(((float)y + 0.5f) / r - 0.5f);
    int ix0 = (int)floorf(((float)x + 0.5f) / r - 0.5f);
    float* base = out + (size_t)(NCH + c) * NCELL;
#pragma unroll
    for (int a = 0; a < 2; ++a) {
        int iy = iy0 + a;
        if (iy < 0 || iy >= OHW) continue;
        float cyv = ((float)iy + 0.5f) * r - 0.5f;
        float wy = fmaxf(0.f, 1.f - fabsf(cyv - (float)y) / r) / S[iy];
#pragma unroll
        for (int b = 0; b < 2; ++b) {
            int ix = ix0 + b;
            if (ix < 0 || ix >= OHW) continue;
            float cxv = ((float)ix + 0.5f) * r - 0.5f;
            float wx = fmaxf(0.f, 1.f - fabsf(cxv - (float)x) / r) / S[ix];
            atomicAdd(base + iy * OHW + ix, e * wy * wx);
        }
    }
}

__global__ void k_mlp_fb(const float* __restrict__ scalar, const float* __restrict__ w1,
                         const float* __restrict__ b1, const float* __restrict__ w2,
                         const float* __restrict__ b2, float* __restrict__ out) {
    __shared__ float h[32];
    int j = threadIdx.x;
    if (j < 32) {
        float a = b1[j];
        for (int i = 0; i < 8; ++i) a = fmaf(scalar[i], w1[i * 32 + j], a);
        h[j] = fmaxf(a, 0.f);
    }
    __syncthreads();
    if (j < 4) {
        float a = b2[j];
        for (int i = 0; i < 32; ++i) a = fmaf(h[i], w2[i * 4 + j], a);
        out[(size_t)(NCH + SDIM) * NCELL + j] = fmaxf(a, 0.f);
    }
}

extern "C" void kernel_launch(void* const* d_in, const int* in_sizes, int n_in,
                              void* d_out, int out_size, void* d_ws, size_t ws_size,
                              hipStream_t stream) {
    const float* spatial = (const float*)d_in[0];
    const float* emb     = (const float*)d_in[1];
    const int*   loc     = (const int*)d_in[2];
    const float* scalar  = (const float*)d_in[3];
    const float* w1      = (const float*)d_in[4];
    const float* b1      = (const float*)d_in[5];
    const float* w2      = (const float*)d_in[6];
    const float* b2      = (const float*)d_in[7];
    float* out = (float*)d_out;

    int*   wsi = (int*)d_ws;
    float* wsf = (float*)d_ws;

    if (ws_size >= WS_REQ_BYTES) {
        int*   counts    = wsi + WS_COUNTS;
        int*   spill_cur = wsi + WS_SPILLCUR;
        float* invS      = wsf + WS_INVS;
        int2*  entries   = (int2*)(wsi + WS_ENTRIES);
        int2*  spill     = (int2*)(wsi + WS_SPILL);
        float* T         = wsf + WS_T;

        k_zero<<<Z_BLOCKS, 256, 0, stream>>>(counts, invS);
        k_phase1<<<FILLB + RY_BLOCKS, 256, 0, stream>>>(spatial, loc, T, counts,
                                                        entries, spill, spill_cur);
        k_phase2<<<GA_BLOCKS + RX_BLOCKS + 1, 256, 0, stream>>>(T, emb, counts, entries,
                                                                spill, spill_cur, invS,
                                                                out, scalar, w1, b1,
                                                                w2, b2);
    } else {
        float* S = wsf;
        hipMemsetAsync(d_out, 0, (size_t)out_size * sizeof(float), stream);
        k_norm_fb<<<1, 128, 0, stream>>>(S);
        k_spatial_fb<<<(NCH * NCELL + 255) / 256, 256, 0, stream>>>(spatial, S, out);
        k_scatter_fb<<<(NPTS * SDIM + 255) / 256, 256, 0, stream>>>(emb, loc, S, out);
        k_mlp_fb<<<1, 64, 0, stream>>>(scalar, w1, b1, w2, b2, out);
    }
}